// Round 7
// baseline (248.906 us; speedup 1.0000x reference)
//
#include <hip/hip_runtime.h>
#include <math.h>

#define N_NODES 10000
#define N_EDGES 320000
#define E_TOT   (N_EDGES + N_NODES)
#define NEG 0.2f

typedef short bf16x8 __attribute__((ext_vector_type(8)));
typedef float f32x4 __attribute__((ext_vector_type(4)));
typedef float f32x2 __attribute__((ext_vector_type(2)));

static __device__ __forceinline__ float4 ld4g(const float* p) { return *(const float4*)p; }

static __device__ __forceinline__ unsigned short f2b(float f) {
    unsigned u;
    __builtin_memcpy(&u, &f, 4);
    unsigned r = (u + 0x7fffu + ((u >> 16) & 1u)) >> 16;   // RNE
    return (unsigned short)r;
}
static __device__ __forceinline__ float b2f(unsigned short u) {
    unsigned x = ((unsigned)u) << 16;
    float f;
    __builtin_memcpy(&f, &x, 4);
    return f;
}
// unpack one dword holding two bf16 (lo = even ch, hi = odd ch) into f32x2
static __device__ __forceinline__ f32x2 unpk(unsigned d) {
    f32x2 r;
    r.x = __uint_as_float(d << 16);
    r.y = __uint_as_float(d & 0xffff0000u);
    return r;
}

// 16-lane (DPP row) rotate-reduction — pure VALU, no DS pipe.
template <int CTRL>
static __device__ __forceinline__ float dpp_add_step(float x) {
    int y = __builtin_amdgcn_update_dpp(0, __float_as_int(x), CTRL, 0xf, 0xf, true);
    return x + __int_as_float(y);
}
static __device__ __forceinline__ float row_sum16(float x) {
    x = dpp_add_step<0x121>(x);   // row_ror:1
    x = dpp_add_step<0x122>(x);   // row_ror:2
    x = dpp_add_step<0x124>(x);   // row_ror:4
    x = dpp_add_step<0x128>(x);   // row_ror:8
    return x;
}

// ---------------- edge dtype detection (int32 vs int64) ----------------
__global__ void detect_dtype_kernel(const int* __restrict__ ei, int* __restrict__ flag) {
    __shared__ int any;
    if (threadIdx.x == 0) any = 0;
    __syncthreads();
    int v = ei[2 * threadIdx.x + 1];
    if (v != 0) atomicOr(&any, 1);
    __syncthreads();
    if (threadIdx.x == 0) *flag = (any == 0) ? 1 : 0;   // 1 => int64
}

static __device__ __forceinline__ int load_edge(const int* ei, int is64, int idx) {
    if (is64) { const long long* e64 = (const long long*)ei; return (int)e64[idx]; }
    return ei[idx];
}

// ---------------- CSR build ----------------
__global__ void count_deg_kernel(const int* __restrict__ ei, const int* __restrict__ flag,
                                 int* __restrict__ deg) {
    int i = blockIdx.x * blockDim.x + threadIdx.x;
    if (i >= E_TOT) return;
    int is64 = *flag;
    int dst = (i < N_EDGES) ? load_edge(ei, is64, N_EDGES + i) : (i - N_EDGES);
    atomicAdd(&deg[dst], 1);
}

__global__ __launch_bounds__(256) void scan_kernel(const int* __restrict__ deg,
                                                   int* __restrict__ row_ptr,
                                                   int* __restrict__ cursor) {
    __shared__ int sums[256];
    int tid = threadIdx.x;
    int base = tid * 40;
    int d40[40];
    int s = 0;
    if (base < N_NODES) {
#pragma unroll
        for (int q = 0; q < 10; ++q) {
            int4 v = *(const int4*)(deg + base + q * 4);
            d40[q * 4 + 0] = v.x; d40[q * 4 + 1] = v.y;
            d40[q * 4 + 2] = v.z; d40[q * 4 + 3] = v.w;
            s += v.x + v.y + v.z + v.w;
        }
    }
    sums[tid] = s;
    __syncthreads();
    int run = s;
    for (int off = 1; off < 256; off <<= 1) {
        int t = (tid >= off) ? sums[tid - off] : 0;
        __syncthreads();
        run += t;
        sums[tid] = run;
        __syncthreads();
    }
    int excl = run - s;
    if (base < N_NODES) {
        int acc = excl;
#pragma unroll
        for (int i = 0; i < 40; ++i) {
            row_ptr[base + i] = acc;
            cursor[base + i] = acc;
            acc += d40[i];
        }
    }
    if (tid == 255) row_ptr[N_NODES] = run;
}

__global__ void fill_csr_kernel(const int* __restrict__ ei, const int* __restrict__ flag,
                                int* __restrict__ cursor, int* __restrict__ csr_src) {
    int i = blockIdx.x * blockDim.x + threadIdx.x;
    if (i >= E_TOT) return;
    int is64 = *flag;
    int src, dst;
    if (i < N_EDGES) { src = load_edge(ei, is64, i); dst = load_edge(ei, is64, N_EDGES + i); }
    else { src = i - N_EDGES; dst = src; }
    int pos = atomicAdd(&cursor[dst], 1);
    csr_src[pos] = src;
}

// ---------------- conversions ----------------
__global__ void convert_x_kernel(const float* __restrict__ x, unsigned short* __restrict__ xb) {
    int i = (blockIdx.x * blockDim.x + threadIdx.x) * 4;
    if (i >= N_NODES * 128) return;
    float4 v = ld4g(x + i);
    ushort4 o = make_ushort4(f2b(v.x), f2b(v.y), f2b(v.z), f2b(v.w));
    *(ushort4*)(xb + i) = o;
}

// Wl,Wr [L][128][512] f32 -> WT [L][1024][128] bf16 transposed
__global__ void convert_wt_kernel(const float* __restrict__ Wl, const float* __restrict__ Wr,
                                  unsigned short* __restrict__ WT) {
    __shared__ float t[32][33];
    int l = blockIdx.z;
    unsigned short* dst = WT + (size_t)l * 1024 * 128;
    int tx = threadIdx.x, ty = threadIdx.y;
    int n0 = blockIdx.x * 32, k0 = blockIdx.y * 32;
    const float* S = ((n0 < 512) ? Wl : Wr) + (size_t)l * 65536;
    int nn0 = n0 & 511;
#pragma unroll
    for (int it = 0; it < 4; ++it) {
        int k = k0 + ty + it * 8;
        t[ty + it * 8][tx] = S[(size_t)k * 512 + nn0 + tx];
    }
    __syncthreads();
#pragma unroll
    for (int it = 0; it < 4; ++it) {
        int n = n0 + ty + it * 8;
        int k = k0 + tx;
        dst[(size_t)n * 128 + k] = f2b(t[tx][ty + it * 8]);
    }
}

// ---------------- MFMA GEMM ----------------
__global__ __launch_bounds__(256) void gemm_mfma_kernel(const unsigned short* __restrict__ A,
                                                        const unsigned short* __restrict__ Bt,
                                                        const float* __restrict__ bl,
                                                        const float* __restrict__ br,
                                                        unsigned short* __restrict__ Y) {
    __shared__ unsigned short As[128][72];
    __shared__ unsigned short Bs[128][72];
    int tid = threadIdx.x;
    int wave = tid >> 6, lane = tid & 63;
    int wm = wave >> 1, wn = wave & 1;
    int l15 = lane & 15, quad = lane >> 4;
    int row0 = blockIdx.y * 128, col0 = blockIdx.x * 128;
    const float* bias = (col0 < 512) ? (bl + col0) : (br + col0 - 512);

    f32x4 acc[4][4];
#pragma unroll
    for (int mi = 0; mi < 4; ++mi)
#pragma unroll
        for (int ni = 0; ni < 4; ++ni)
#pragma unroll
            for (int r = 0; r < 4; ++r) acc[mi][ni][r] = 0.f;

#pragma unroll
    for (int kc = 0; kc < 2; ++kc) {
#pragma unroll
        for (int it = 0; it < 4; ++it) {
            int e = tid + it * 256;
            int r = e >> 3, s = e & 7;
            int gr = row0 + r;
            bf16x8 v = (bf16x8)(short)0;
            if (gr < N_NODES) v = *(const bf16x8*)(A + (size_t)gr * 128 + kc * 64 + s * 8);
            *(bf16x8*)&As[r][s * 8] = v;
            bf16x8 w = *(const bf16x8*)(Bt + (size_t)(col0 + r) * 128 + kc * 64 + s * 8);
            *(bf16x8*)&Bs[r][s * 8] = w;
        }
        __syncthreads();
#pragma unroll
        for (int kq = 0; kq < 2; ++kq) {
            bf16x8 af[4], bfr[4];
#pragma unroll
            for (int mi = 0; mi < 4; ++mi)
                af[mi] = *(const bf16x8*)&As[wm * 64 + mi * 16 + l15][kq * 32 + quad * 8];
#pragma unroll
            for (int ni = 0; ni < 4; ++ni)
                bfr[ni] = *(const bf16x8*)&Bs[wn * 64 + ni * 16 + l15][kq * 32 + quad * 8];
#pragma unroll
            for (int mi = 0; mi < 4; ++mi)
#pragma unroll
                for (int ni = 0; ni < 4; ++ni)
                    acc[mi][ni] = __builtin_amdgcn_mfma_f32_16x16x32_bf16(af[mi], bfr[ni], acc[mi][ni], 0, 0, 0);
        }
        __syncthreads();
    }

    float bv[4];
#pragma unroll
    for (int ni = 0; ni < 4; ++ni) bv[ni] = bias[wn * 64 + ni * 16 + l15];

#pragma unroll
    for (int mi = 0; mi < 4; ++mi) {
#pragma unroll
        for (int r = 0; r < 4; ++r) {
            int grow = row0 + wm * 64 + mi * 16 + quad * 4 + r;
            if (grow >= N_NODES) continue;
#pragma unroll
            for (int ni = 0; ni < 4; ++ni) {
                int gcol = col0 + wn * 64 + ni * 16 + l15;
                Y[(size_t)grow * 1024 + gcol] = f2b(acc[mi][ni][r] + bv[ni]);
            }
        }
    }
}

// ---------------- fused attention: TWO waves per dst (split row), deferred softmax ----------------
// Block = 4 waves = 2 dsts. Wave pair (primary, secondary) splits the dst's edge range in half;
// partials (d, acc[8]) merge linearly via LDS (deferred softmax — no rescale needed).
// lane = h*16 + g; lane holds channels [8g..8g+7] of head h (offset 8*lane in the 512 block).
__global__ __launch_bounds__(256) void attn_kernel(
    const unsigned short* __restrict__ xlr,   // [n][1024] bf16: xl | xr
    const float* __restrict__ x_in, const int* __restrict__ row_ptr,
    const int* __restrict__ csr_src, const float* __restrict__ att,
    const float* __restrict__ bias, const float* __restrict__ ln_g,
    const float* __restrict__ ln_b, float* __restrict__ x_out,
    unsigned short* __restrict__ xb_out) {
    int wid = threadIdx.x >> 6;
    int lane = threadIdx.x & 63;
    int pair = wid >> 1;
    int half = wid & 1;
    int dst = blockIdx.x * 2 + pair;      // grid = N_NODES/2 exactly
    int g = lane & 15;
    int off = 8 * lane;

    f32x2 xr2[4], at2[4];
    {
        uint4 u = *(const uint4*)(xlr + (size_t)dst * 1024 + 512 + off);
        xr2[0] = unpk(u.x); xr2[1] = unpk(u.y); xr2[2] = unpk(u.z); xr2[3] = unpk(u.w);
        float4 a = ld4g(att + off);
        float4 b = ld4g(att + off + 4);
        at2[0].x = a.x; at2[0].y = a.y; at2[1].x = a.z; at2[1].y = a.w;
        at2[2].x = b.x; at2[2].y = b.y; at2[3].x = b.z; at2[3].y = b.w;
    }
    const f32x2 neg2 = {NEG, NEG};

    float d = 0.f;
    f32x2 acc2[4] = {{0.f, 0.f}, {0.f, 0.f}, {0.f, 0.f}, {0.f, 0.f}};

    int beg = row_ptr[dst], end = row_ptr[dst + 1];
    int len = end - beg;
    int h0 = (len + 1) >> 1;
    int b = half ? (beg + h0) : beg;
    int e = half ? end : (beg + h0);

    int nfull = (e - b) & ~3;
    int pend = b + nfull;
    int p = b;

    if (nfull) {
        int s0 = csr_src[p], s1 = csr_src[p + 1], s2 = csr_src[p + 2], s3 = csr_src[p + 3];
        uint4 u0 = *(const uint4*)(xlr + (size_t)s0 * 1024 + off);
        uint4 u1 = *(const uint4*)(xlr + (size_t)s1 * 1024 + off);
        uint4 u2 = *(const uint4*)(xlr + (size_t)s2 * 1024 + off);
        uint4 u3 = *(const uint4*)(xlr + (size_t)s3 * 1024 + off);
        while (true) {
            p += 4;
            bool more = p < pend;
            uint4 n0, n1, n2, n3;
            if (more) {
                int t0 = csr_src[p], t1 = csr_src[p + 1], t2 = csr_src[p + 2], t3 = csr_src[p + 3];
                n0 = *(const uint4*)(xlr + (size_t)t0 * 1024 + off);
                n1 = *(const uint4*)(xlr + (size_t)t1 * 1024 + off);
                n2 = *(const uint4*)(xlr + (size_t)t2 * 1024 + off);
                n3 = *(const uint4*)(xlr + (size_t)t3 * 1024 + off);
            }
            // unpack once, keep fragments in registers
            f32x2 F0[4], F1[4], F2[4], F3[4];
            {
                const unsigned* w0 = (const unsigned*)&u0;
                const unsigned* w1 = (const unsigned*)&u1;
                const unsigned* w2 = (const unsigned*)&u2;
                const unsigned* w3 = (const unsigned*)&u3;
#pragma unroll
                for (int q = 0; q < 4; ++q) {
                    F0[q] = unpk(w0[q]); F1[q] = unpk(w1[q]);
                    F2[q] = unpk(w2[q]); F3[q] = unpk(w3[q]);
                }
            }
            f32x2 q0 = {0.f, 0.f}, q1 = {0.f, 0.f}, q2 = {0.f, 0.f}, q3 = {0.f, 0.f};
#pragma unroll
            for (int q = 0; q < 4; ++q) {
                f32x2 s;
                s = F0[q] + xr2[q]; s = __builtin_elementwise_max(s, s * neg2);
                q0 = __builtin_elementwise_fma(s, at2[q], q0);
                s = F1[q] + xr2[q]; s = __builtin_elementwise_max(s, s * neg2);
                q1 = __builtin_elementwise_fma(s, at2[q], q1);
                s = F2[q] + xr2[q]; s = __builtin_elementwise_max(s, s * neg2);
                q2 = __builtin_elementwise_fma(s, at2[q], q2);
                s = F3[q] + xr2[q]; s = __builtin_elementwise_max(s, s * neg2);
                q3 = __builtin_elementwise_fma(s, at2[q], q3);
            }
            float p0 = row_sum16(q0.x + q0.y);
            float p1 = row_sum16(q1.x + q1.y);
            float p2 = row_sum16(q2.x + q2.y);
            float p3 = row_sum16(q3.x + q3.y);
            float e0 = __expf(p0), e1 = __expf(p1), e2 = __expf(p2), e3 = __expf(p3);
            d += (e0 + e1) + (e2 + e3);
            f32x2 W0 = {e0, e0}, W1 = {e1, e1}, W2 = {e2, e2}, W3 = {e3, e3};
#pragma unroll
            for (int q = 0; q < 4; ++q) {
                f32x2 t = __builtin_elementwise_fma(F0[q], W0, acc2[q]);
                t = __builtin_elementwise_fma(F1[q], W1, t);
                t = __builtin_elementwise_fma(F2[q], W2, t);
                acc2[q] = __builtin_elementwise_fma(F3[q], W3, t);
            }
            if (!more) break;
            u0 = n0; u1 = n1; u2 = n2; u3 = n3;
        }
    }
    for (; p < e; ++p) {
        int s0 = csr_src[p];
        uint4 u0 = *(const uint4*)(xlr + (size_t)s0 * 1024 + off);
        const unsigned* w0 = (const unsigned*)&u0;
        f32x2 F0[4];
#pragma unroll
        for (int q = 0; q < 4; ++q) F0[q] = unpk(w0[q]);
        f32x2 q0 = {0.f, 0.f};
#pragma unroll
        for (int q = 0; q < 4; ++q) {
            f32x2 s = F0[q] + xr2[q];
            s = __builtin_elementwise_max(s, s * neg2);
            q0 = __builtin_elementwise_fma(s, at2[q], q0);
        }
        float p0 = row_sum16(q0.x + q0.y);
        float e0 = __expf(p0);
        d += e0;
        f32x2 W0 = {e0, e0};
#pragma unroll
        for (int q = 0; q < 4; ++q)
            acc2[q] = __builtin_elementwise_fma(F0[q], W0, acc2[q]);
    }

    // ---- merge halves via LDS (deferred softmax: linear combine) ----
    __shared__ float pa[2][64][9];
    if (half) {
        pa[pair][lane][0] = acc2[0].x; pa[pair][lane][1] = acc2[0].y;
        pa[pair][lane][2] = acc2[1].x; pa[pair][lane][3] = acc2[1].y;
        pa[pair][lane][4] = acc2[2].x; pa[pair][lane][5] = acc2[2].y;
        pa[pair][lane][6] = acc2[3].x; pa[pair][lane][7] = acc2[3].y;
        pa[pair][lane][8] = d;
    }
    __syncthreads();
    if (half) return;
    acc2[0].x += pa[pair][lane][0]; acc2[0].y += pa[pair][lane][1];
    acc2[1].x += pa[pair][lane][2]; acc2[1].y += pa[pair][lane][3];
    acc2[2].x += pa[pair][lane][4]; acc2[2].y += pa[pair][lane][5];
    acc2[3].x += pa[pair][lane][6]; acc2[3].y += pa[pair][lane][7];
    d += pa[pair][lane][8];

    float inv = 1.f / d;
    float t[8];
#pragma unroll
    for (int q = 0; q < 4; ++q) {
        t[2 * q] = acc2[q].x * inv;
        t[2 * q + 1] = acc2[q].y * inv;
    }
#pragma unroll
    for (int j = 0; j < 8; ++j) {   // cross-head sum, once per node
        t[j] += __shfl_xor(t[j], 16, 64);
        t[j] += __shfl_xor(t[j], 32, 64);
    }
    float4 bi0 = ld4g(bias + 8 * g), bi1 = ld4g(bias + 8 * g + 4);
    float4 xi0 = ld4g(x_in + (size_t)dst * 128 + 8 * g);
    float4 xi1 = ld4g(x_in + (size_t)dst * 128 + 8 * g + 4);
    float hc[8];
    hc[0] = t[0] * 0.25f + bi0.x + xi0.x;
    hc[1] = t[1] * 0.25f + bi0.y + xi0.y;
    hc[2] = t[2] * 0.25f + bi0.z + xi0.z;
    hc[3] = t[3] * 0.25f + bi0.w + xi0.w;
    hc[4] = t[4] * 0.25f + bi1.x + xi1.x;
    hc[5] = t[5] * 0.25f + bi1.y + xi1.y;
    hc[6] = t[6] * 0.25f + bi1.z + xi1.z;
    hc[7] = t[7] * 0.25f + bi1.w + xi1.w;

    float sm = 0.f, sq = 0.f;
#pragma unroll
    for (int j = 0; j < 8; ++j) { sm += hc[j]; sq = fmaf(hc[j], hc[j], sq); }
    sm = row_sum16(sm);
    sq = row_sum16(sq);
    float mu = sm * (1.f / 128.f);
    float var = sq * (1.f / 128.f) - mu * mu;
    float rs = rsqrtf(var + 1e-5f);
    float4 g0 = ld4g(ln_g + 8 * g), g1 = ld4g(ln_g + 8 * g + 4);
    float4 b0 = ld4g(ln_b + 8 * g), b1 = ld4g(ln_b + 8 * g + 4);
    float y[8];
    y[0] = fmaxf((hc[0] - mu) * rs * g0.x + b0.x, 0.f);
    y[1] = fmaxf((hc[1] - mu) * rs * g0.y + b0.y, 0.f);
    y[2] = fmaxf((hc[2] - mu) * rs * g0.z + b0.z, 0.f);
    y[3] = fmaxf((hc[3] - mu) * rs * g0.w + b0.w, 0.f);
    y[4] = fmaxf((hc[4] - mu) * rs * g1.x + b1.x, 0.f);
    y[5] = fmaxf((hc[5] - mu) * rs * g1.y + b1.y, 0.f);
    y[6] = fmaxf((hc[6] - mu) * rs * g1.z + b1.z, 0.f);
    y[7] = fmaxf((hc[7] - mu) * rs * g1.w + b1.w, 0.f);

    if (lane < 16) {
        float4 o0 = make_float4(y[0], y[1], y[2], y[3]);
        float4 o1 = make_float4(y[4], y[5], y[6], y[7]);
        *(float4*)(x_out + (size_t)dst * 128 + 8 * g) = o0;
        *(float4*)(x_out + (size_t)dst * 128 + 8 * g + 4) = o1;
        if (xb_out) {
            ushort4 c0 = make_ushort4(f2b(y[0]), f2b(y[1]), f2b(y[2]), f2b(y[3]));
            ushort4 c1 = make_ushort4(f2b(y[4]), f2b(y[5]), f2b(y[6]), f2b(y[7]));
            *(ushort4*)(xb_out + (size_t)dst * 128 + 8 * g) = c0;
            *(ushort4*)(xb_out + (size_t)dst * 128 + 8 * g + 4) = c1;
        }
    }
}

// ---------------- launcher ----------------
extern "C" void kernel_launch(void* const* d_in, const int* in_sizes, int n_in,
                              void* d_out, int out_size, void* d_ws, size_t ws_size,
                              hipStream_t stream) {
    const float* x    = (const float*)d_in[0];
    const int*   ei   = (const int*)d_in[1];
    const float* Wl   = (const float*)d_in[2];
    const float* bl   = (const float*)d_in[3];
    const float* Wr   = (const float*)d_in[4];
    const float* br   = (const float*)d_in[5];
    const float* att  = (const float*)d_in[6];
    const float* bias = (const float*)d_in[7];
    const float* lng  = (const float*)d_in[8];
    const float* lnb  = (const float*)d_in[9];
    float* out = (float*)d_out;

    char* ws = (char*)d_ws;
    unsigned short* xlr = (unsigned short*)ws; ws += (size_t)N_NODES * 1024 * 2;
    float* xbuf  = (float*)ws;          ws += (size_t)N_NODES * 128 * 4;
    unsigned short* xb = (unsigned short*)ws; ws += (size_t)N_NODES * 128 * 2;
    unsigned short* WT = (unsigned short*)ws; ws += (size_t)2 * 1024 * 128 * 2;
    int* deg     = (int*)ws;            ws += (size_t)N_NODES * 4;
    int* row_ptr = (int*)ws;            ws += (size_t)(N_NODES + 4) * 4;
    int* cursor  = (int*)ws;            ws += (size_t)N_NODES * 4;
    int* csr_src = (int*)ws;            ws += (size_t)E_TOT * 4;
    int* flag    = (int*)ws;            ws += 256;

    hipMemsetAsync(deg, 0, N_NODES * sizeof(int), stream);
    detect_dtype_kernel<<<1, 256, 0, stream>>>(ei, flag);
    count_deg_kernel<<<(E_TOT + 255) / 256, 256, 0, stream>>>(ei, flag, deg);
    scan_kernel<<<1, 256, 0, stream>>>(deg, row_ptr, cursor);
    fill_csr_kernel<<<(E_TOT + 255) / 256, 256, 0, stream>>>(ei, flag, cursor, csr_src);

    convert_wt_kernel<<<dim3(32, 4, 2), dim3(32, 8), 0, stream>>>(Wl, Wr, WT);
    convert_x_kernel<<<(N_NODES * 128 / 4 + 255) / 256, 256, 0, stream>>>(x, xb);

    for (int l = 0; l < 2; ++l) {
        const float* xin = (l == 0) ? x : xbuf;
        float* xout = (l == 0) ? xbuf : out;
        unsigned short* xbo = (l == 0) ? xb : (unsigned short*)nullptr;
        gemm_mfma_kernel<<<dim3(8, 79), 256, 0, stream>>>(xb, WT + (size_t)l * 1024 * 128, bl + (size_t)l * 512,
                                                          br + (size_t)l * 512, xlr);
        attn_kernel<<<N_NODES / 2, 256, 0, stream>>>(
            xlr, xin, row_ptr, csr_src,
            att + (size_t)l * 512, bias + (size_t)l * 128,
            lng + (size_t)l * 128, lnb + (size_t)l * 128, xout, xbo);
    }
}